// Round 2
// baseline (205.720 us; speedup 1.0000x reference)
//
#include <hip/hip_runtime.h>
#include <cmath>

// ---------------------------------------------------------------------------
// SwinV2-style window attention, f16-MFMA implementation.  Round 9b.
//
// R8->R9 (attn_mfma only):
//  * run_l via ones-column MFMA: accl = mfma(P, 1, accl) gives the softmax
//    denominator directly in the O output layout -> deletes 512 v_add/wave
//    and the whole shfl_xor/shfl epilogue redistribution.
//  * P f32->f16 via v_cvt_pkrtz (2 floats/inst instead of cvt+cvt+pack).
//  * explicit 2-deep software pipeline: per kt the order is
//    QK(s0) -> PV(prev kt, s1) -> exp/write(s0) -> QK(s1) ->
//    prefetch K/V(kt+1) -> PV(kt, s0) -> exp/write(s1),
//    with per-wave DUAL P-buffers (pa 20KB) and double-buffered V regs.
//    Every LDS write->read pair and every global load has a full compute
//    phase in between; K/V stay L2-resident (XCD-congruent grid as in R8).
//  R9b: fix cvt_pkrtz result type (__fp16 vector, bit-cast to uint).
// ---------------------------------------------------------------------------

typedef _Float16 half_t;
typedef __attribute__((ext_vector_type(2))) __fp16 fp16x2;
typedef __attribute__((ext_vector_type(4))) _Float16 half4;
typedef __attribute__((ext_vector_type(8))) _Float16 half8;
typedef __attribute__((ext_vector_type(4))) float float4v;
typedef __attribute__((ext_vector_type(2))) unsigned int uint2v;

static __device__ __forceinline__ float4v mfma16(half8 a, half8 b, float4v c) {
  return __builtin_amdgcn_mfma_f32_16x16x32_f16(a, b, c, 0, 0, 0);
}

struct PtrArr8 { const float* p[8]; };

// ---------------------------------------------------------------------------
// prep_w: fp32 W -> f16 (+I for qkv), PRE-FRAGMENTED B-layout:
// wf[y*16384 + ((ng*4+ks)*64 + quad*16 + l)*8 + (k&7)] = W[j=ng*16+l][k](+I)
// grid (16, 8) x 256.  Biases packed to bws[y][128].
// ---------------------------------------------------------------------------
__global__ __launch_bounds__(256) void prep_w(PtrArr8 wsrc, PtrArr8 bsrc,
                                              half_t* __restrict__ wf,
                                              float* __restrict__ bws) {
  int y = blockIdx.y;
  const float* src = nullptr;
  const float* bs = nullptr;
#pragma unroll
  for (int i = 0; i < 8; i++)
    if (i == y) { src = wsrc.p[i]; bs = bsrc.p[i]; }
  int flat = (blockIdx.x * 256 + threadIdx.x) * 4;
  float4 w = *(const float4*)(src + flat);
  int j = flat >> 7, k = flat & 127;
  if (y < 6) {
    if (k == j)     w.x += 1.0f;
    if (k + 1 == j) w.y += 1.0f;
    if (k + 2 == j) w.z += 1.0f;
    if (k + 3 == j) w.w += 1.0f;
  }
  half4 h;
  h[0] = (half_t)w.x;
  h[1] = (half_t)w.y;
  h[2] = (half_t)w.z;
  h[3] = (half_t)w.w;
  int ng = j >> 4, l = j & 15, ks = k >> 5, quad = (k >> 3) & 3, o8 = k & 7;
  *(half4*)(wf + y * 16384 + ((ng * 4 + ks) * 64 + quad * 16 + l) * 8 + o8) =
      h;
  if (blockIdx.x == 0 && threadIdx.x < 128)
    bws[y * 128 + threadIdx.x] = bs[threadIdx.x];
}

// ---------------------------------------------------------------------------
// bias_mlp: tabh2[h][p] = 16*sigmoid(mlp(...))*log2e + c14(h), 63x63 grid.
// c14(h) = 14 - (scale_h + 16)*log2e; makes attn P~ = exp2(mfma result).
// ---------------------------------------------------------------------------
__global__ __launch_bounds__(256) void bias_mlp(const float* __restrict__ w1,
                                                const float* __restrict__ b1,
                                                const float* __restrict__ w2,
                                                const float* __restrict__ ls,
                                                float* __restrict__ tabh2) {
  __shared__ float sw1[256];
  __shared__ float sb1[128];
  __shared__ float sw2[1024];
  int t = threadIdx.x;
  sw1[t] = w1[t];
  if (t < 128) sb1[t] = b1[t];
  for (int i = t; i < 1024; i += 256) sw2[i] = w2[i];
  __syncthreads();
  int p = blockIdx.x * 256 + t;
  if (p >= 3969) return;
  int ph = p / 63, pw = p % 63;
  float t0 = (float)(ph - 31) * (3.2f / 31.0f);
  float t1 = (float)(pw - 31) * (3.2f / 31.0f);
  t0 = copysignf(1.0f - __expf(-fabsf(t0)), t0);
  t1 = copysignf(1.0f - __expf(-fabsf(t1)), t1);
  float acc[8];
#pragma unroll
  for (int hh = 0; hh < 8; hh++) acc[hh] = 0.0f;
  for (int j = 0; j < 128; j++) {
    float hj = fmaxf(0.0f, t0 * sw1[2 * j] + t1 * sw1[2 * j + 1] + sb1[j]);
#pragma unroll
    for (int hh = 0; hh < 8; hh++) acc[hh] += hj * sw2[hh * 128 + j];
  }
  const float L2E = 1.44269504f;
#pragma unroll
  for (int hh = 0; hh < 8; hh++) {
    float scale = __expf(fminf(ls[hh], 4.6051702f));
    float c14 = 14.0f - (scale + 16.0f) * L2E;
    float bias = 16.0f / (1.0f + __expf(-acc[hh]));
    tabh2[hh * 3969 + p] = bias * L2E + c14;
  }
}

// ---------------------------------------------------------------------------
// qkv_mfma: 3 fused linears (residual folded into W), per-head q/k norm,
// q scaled by scale*log2e.  grid (512 rowtiles-of-32, 2 hf) x 256.
// Wave (rw,cw): rows rw*16..+15, cols cw*64..+63.  W-frags direct from
// global pre-fragmented layout (1KB contiguous wave loads).  LDS only for
// the epilogue transpose.
// ---------------------------------------------------------------------------
__global__ __launch_bounds__(256, 4) void qkv_mfma(
    const float* __restrict__ x, const half_t* __restrict__ wfrag,
    const float* __restrict__ lscale, const float* __restrict__ bws,
    half_t* __restrict__ qf, half_t* __restrict__ kf,
    half_t* __restrict__ vf) {
  __shared__ half_t tbuf[4608];  // q/k: [32][136]; v: [128][36]
  int t = threadIdx.x;
  int lane = t & 63, wv = t >> 6, l = lane & 15, quad = lane >> 4;
  int rw = wv & 1, cw = wv >> 1;
  int hf = blockIdx.y;
  int m0 = blockIdx.x * 32;
  int b = m0 >> 10, n0 = m0 & 1023;

  // A fragments: 16 rows (rw strip), this half's 128 channels.
  half8 afr[4];
  {
    const float* xb =
        x + ((size_t)b * 256 + hf * 128) * 1024 + n0 + rw * 16 + l;
#pragma unroll
    for (int ks = 0; ks < 4; ks++) {
      half8 a;
#pragma unroll
      for (int j = 0; j < 8; j++)
        a[j] = (half_t)xb[(size_t)(ks * 32 + quad * 8 + j) * 1024];
      afr[ks] = a;
    }
  }

  for (int op = 0; op < 3; op++) {
    int combo = op * 2 + hf;
    const half_t* wfb = wfrag + combo * 16384;
    float4v acc[4];
#pragma unroll
    for (int ngl = 0; ngl < 4; ngl++) {
      int ng = cw * 4 + ngl;
      float4v c = {0.f, 0.f, 0.f, 0.f};
#pragma unroll
      for (int ks = 0; ks < 4; ks++) {
        half8 bfrag =
            *(const half8*)(wfb + ((ng * 4 + ks) * 64 + lane) * 8);
        c = mfma16(afr[ks], bfrag, c);
      }
      acc[ngl] = c;
    }
#pragma unroll
    for (int ngl = 0; ngl < 4; ngl++) {
      float bb = bws[combo * 128 + (cw * 4 + ngl) * 16 + l];
#pragma unroll
      for (int r2 = 0; r2 < 4; r2++) acc[ngl][r2] += bb;
    }
    if (op < 2) {
      // normalize per head: this wave's heads = hf*4 + cw*2 + {0,1}
#pragma unroll
      for (int hgl = 0; hgl < 2; hgl++) {
        float sc = 1.0f;
        if (op == 0)
          sc = __expf(fminf(lscale[hf * 4 + cw * 2 + hgl], 4.6051702f)) *
               1.44269504f;
#pragma unroll
        for (int r2 = 0; r2 < 4; r2++) {
          float ss = acc[2 * hgl][r2] * acc[2 * hgl][r2] +
                     acc[2 * hgl + 1][r2] * acc[2 * hgl + 1][r2];
          ss += __shfl_xor(ss, 1, 64);
          ss += __shfl_xor(ss, 2, 64);
          ss += __shfl_xor(ss, 4, 64);
          ss += __shfl_xor(ss, 8, 64);
          float rn = sc / fmaxf(sqrtf(ss), 1e-12f);
          acc[2 * hgl][r2] *= rn;
          acc[2 * hgl + 1][r2] *= rn;
        }
      }
      // transpose via LDS [row32][col128] stride 136 -> coalesced half8
#pragma unroll
      for (int ngl = 0; ngl < 4; ngl++)
#pragma unroll
        for (int r2 = 0; r2 < 4; r2++)
          tbuf[(rw * 16 + quad * 4 + r2) * 136 + (cw * 4 + ngl) * 16 + l] =
              (half_t)acc[ngl][r2];
      __syncthreads();
      half_t* dst = (op == 0) ? qf : kf;
#pragma unroll
      for (int i = 0; i < 2; i++) {
        int idx = t + 256 * i;
        int row = idx >> 4, colc = (idx & 15) * 8;
        half8 vv = *(const half8*)(tbuf + row * 136 + colc);
        int head = hf * 4 + (colc >> 5), d = colc & 31;
        *(half8*)(dst + (((size_t)b * 8 + head) * 1024 + n0 + row) * 32 + d) =
            vv;
      }
      __syncthreads();
    } else {
      // v: [col128][row32] stride 36 -> coalesced dword to [b][h][d][n]
#pragma unroll
      for (int ngl = 0; ngl < 4; ngl++) {
        int col = (cw * 4 + ngl) * 16 + l;
        half4 hv;
#pragma unroll
        for (int r2 = 0; r2 < 4; r2++) hv[r2] = (half_t)acc[ngl][r2];
        *(half4*)(tbuf + col * 36 + rw * 16 + quad * 4) = hv;
      }
      __syncthreads();
#pragma unroll
      for (int i = 0; i < 8; i++) {
        int idx = t + 256 * i;
        int col = idx >> 4, rp = idx & 15;
        unsigned int val = *(const unsigned int*)(tbuf + col * 36 + rp * 2);
        int head = hf * 4 + (col >> 5);
        int d = col & 31;
        *(unsigned int*)((char*)vf +
                         (((((size_t)b * 8 + head) * 32 + d) * 1024) + n0 +
                          rp * 2) * 2) = val;
      }
    }
  }
}

// ---------------------------------------------------------------------------
// attn_mfma: barrier-free flash attention, XCD-local K/V, software-pipelined.
// 1-D grid 1024: id = qo*128 + (b*8+h) -> the 8 qo-blocks of one (b,h) are
// congruent mod 8 -> same XCD -> K/V L2-resident.  256 thr (4 waves), wave
// owns 32 q-rows = one image row.  P~ = exp2(QK + biastab).
// Softmax denominator via ones-column MFMA (accl = mfma(P,1,accl): row sum
// lands directly in the O layout, row = quad*4+r2).  Dual per-wave P LDS
// buffers + double-buffered V regs give every LDS write->read and global
// load a full compute phase of slack.
// ---------------------------------------------------------------------------

#define LOADKV(kt, VV)                                                      \
  {                                                                         \
    _Pragma("unroll") for (int nt = 0; nt < 4; nt++)                        \
        kfr[nt] = *(const half8*)(kbase + ((kt)*64 + nt * 16 + l) * 32 +    \
                                  quad * 8);                                \
    _Pragma("unroll") for (int ks = 0; ks < 2; ks++) {                      \
      VV[0][ks] = *(const half8*)(vbase + l * 1024 + (kt)*64 + ks * 32 +    \
                                  quad * 8);                                \
      VV[1][ks] = *(const half8*)(vbase + (16 + l) * 1024 + (kt)*64 +       \
                                  ks * 32 + quad * 8);                      \
    }                                                                       \
  }

#define QK_PHASE(kt, S, SR)                                                 \
  {                                                                         \
    int rowb = (wv + 31 - 2 * (kt)) * 63 + cA + (S)*16;                     \
    _Pragma("unroll") for (int nt = 0; nt < 4; nt++) {                      \
      int base = rowb - (nt >> 1) * 63 - (nt & 1) * 16;                     \
      float4v c;                                                            \
      c[0] = sb2[base];                                                     \
      c[1] = sb2[base - 1];                                                 \
      c[2] = sb2[base - 2];                                                 \
      c[3] = sb2[base - 3];                                                 \
      SR[nt] = mfma16(kfr[nt], qfr[S], c);                                  \
    }                                                                       \
  }

#define EXP_WRITE(S, SR)                                                    \
  {                                                                         \
    half_t* paws = pa + (wv * 2 + (S)) * 1280;                              \
    _Pragma("unroll") for (int nt = 0; nt < 4; nt++) {                      \
      fp16x2 plo = __builtin_amdgcn_cvt_pkrtz(exp2f(SR[nt][0]),             \
                                              exp2f(SR[nt][1]));            \
      fp16x2 phi = __builtin_amdgcn_cvt_pkrtz(exp2f(SR[nt][2]),             \
                                              exp2f(SR[nt][3]));            \
      uint2v uu;                                                            \
      uu.x = __builtin_bit_cast(unsigned int, plo);                         \
      uu.y = __builtin_bit_cast(unsigned int, phi);                         \
      *(uint2v*)(paws + l * 80 + nt * 16 + quad * 4) = uu;                  \
    }                                                                       \
  }

#define PV_PHASE(S, VV)                                                     \
  {                                                                         \
    const half_t* paws = pa + (wv * 2 + (S)) * 1280;                        \
    _Pragma("unroll") for (int ks = 0; ks < 2; ks++) {                      \
      half8 pfr = *(const half8*)(paws + l * 80 + ks * 32 + quad * 8);      \
      o0[S] = mfma16(pfr, VV[0][ks], o0[S]);                                \
      o1[S] = mfma16(pfr, VV[1][ks], o1[S]);                                \
      accl[S] = mfma16(pfr, ones, accl[S]);                                 \
    }                                                                       \
  }

// phase order per kt: QK(s0) -> PV(prev kt,s1) -> exp/wr(s0) -> QK(s1) ->
// prefetch(kt+1) -> PV(kt,s0) -> exp/wr(s1)
#define ITER(kt, VC, VN, DO_PREV, DO_PREF)                                  \
  {                                                                         \
    float4v sres[4];                                                        \
    QK_PHASE(kt, 0, sres);                                                  \
    if (DO_PREV) PV_PHASE(1, VN);                                           \
    EXP_WRITE(0, sres);                                                     \
    float4v sres2[4];                                                       \
    QK_PHASE(kt, 1, sres2);                                                 \
    if (DO_PREF) LOADKV((kt) + 1, VN);                                      \
    PV_PHASE(0, VC);                                                        \
    EXP_WRITE(1, sres2);                                                    \
  }

__global__ __launch_bounds__(256, 4) void attn_mfma(
    const half_t* __restrict__ qf, const half_t* __restrict__ kf,
    const half_t* __restrict__ vf, const float* __restrict__ tabh2,
    half_t* __restrict__ ao) {
  __shared__ float sb2[35 * 63];    // bias slice: dih-local in [0,35)
  __shared__ half_t pa[10240];      // per-wave dual P~ buffers [16][80]

  int id = blockIdx.x;
  int qo = id >> 7;
  int bh = id & 127;
  int h = bh & 7, b = bh >> 3;
  int t = threadIdx.x;
  int lane = t & 63, wv = t >> 6, l = lane & 15, quad = lane >> 4;
  size_t bhs = (size_t)b * 8 + h;
  const half_t* kbase = kf + bhs * 1024 * 32;
  const half_t* vbase = vf + bhs * 32 * 1024;
  int row0 = qo * 128 + wv * 32;
  int cA = l + 31 - quad * 4;

  half8 kfr[4], va[2][2], vb[2][2], qfr[2];
  LOADKV(0, va);
#pragma unroll
  for (int s = 0; s < 2; s++)
    qfr[s] = *(const half8*)(qf + (bhs * 1024 + row0 + s * 16 + l) * 32 +
                             quad * 8);

  // stage bias slice: dih_global in [qo*4, qo*4+35)
  for (int i = t; i < 2205; i += 256)
    sb2[i] = tabh2[h * 3969 + qo * 252 + i];

  float4v o0[2], o1[2], accl[2];
#pragma unroll
  for (int s = 0; s < 2; s++) {
    o0[s] = (float4v){0.f, 0.f, 0.f, 0.f};
    o1[s] = (float4v){0.f, 0.f, 0.f, 0.f};
    accl[s] = (float4v){0.f, 0.f, 0.f, 0.f};
  }
  half8 ones;
#pragma unroll
  for (int j = 0; j < 8; j++) ones[j] = (half_t)1.0f;

  __syncthreads();  // the ONLY barrier

  ITER(0, va, vb, 0, 1);
  ITER(1, vb, va, 1, 1);
  for (int kt2 = 2; kt2 < 14; kt2 += 2) {
    ITER(kt2, va, vb, 1, 1);
    ITER(kt2 + 1, vb, va, 1, 1);
  }
  ITER(14, va, vb, 1, 1);
  ITER(15, vb, va, 1, 0);
  PV_PHASE(1, vb);  // drain (kt=15, s=1)

#pragma unroll
  for (int s = 0; s < 2; s++) {
#pragma unroll
    for (int r2 = 0; r2 < 4; r2++) {
      float linv = 1.0f / accl[s][r2];
      size_t rowaddr =
          ((size_t)b * 1024 + row0 + s * 16 + quad * 4 + r2) * 256 + h * 32;
      ao[rowaddr + l] = (half_t)(o0[s][r2] * linv);
      ao[rowaddr + 16 + l] = (half_t)(o1[s][r2] * linv);
    }
  }
}

// ---------------------------------------------------------------------------
// proj_mfma: output projection, fp32 out [b][ch][n] via LDS transpose.
// grid (512 rowtiles-of-32, 2 hf) x 256.  W-frags direct from global.
// ---------------------------------------------------------------------------
__global__ __launch_bounds__(256, 4) void proj_mfma(
    const half_t* __restrict__ ao, const half_t* __restrict__ wfrag,
    const float* __restrict__ bws, float* __restrict__ out) {
  __shared__ float yt[128 * 36];
  int t = threadIdx.x;
  int lane = t & 63, wv = t >> 6, l = lane & 15, quad = lane >> 4;
  int rw = wv & 1, cw = wv >> 1;
  int hf = blockIdx.y;
  int m0 = blockIdx.x * 32;
  int b = m0 >> 10, n0 = m0 & 1023;

  half8 afr[4];
  const half_t* ab =
      ao + ((size_t)m0 + rw * 16 + l) * 256 + hf * 128 + quad * 8;
#pragma unroll
  for (int ks = 0; ks < 4; ks++) afr[ks] = *(const half8*)(ab + ks * 32);

  const half_t* wfb = wfrag + (6 + hf) * 16384;
#pragma unroll
  for (int ngl = 0; ngl < 4; ngl++) {
    int ng = cw * 4 + ngl;
    float4v c = {0.f, 0.f, 0.f, 0.f};
#pragma unroll
    for (int ks = 0; ks < 4; ks++) {
      half8 bfrag = *(const half8*)(wfb + ((ng * 4 + ks) * 64 + lane) * 8);
      c = mfma16(afr[ks], bfrag, c);
    }
    float bb = bws[(6 + hf) * 128 + ng * 16 + l];
#pragma unroll
    for (int r2 = 0; r2 < 4; r2++) c[r2] += bb;
    *(float4v*)(yt + (ng * 16 + l) * 36 + rw * 16 + quad * 4) = c;
  }
  __syncthreads();
#pragma unroll
  for (int i = 0; i < 4; i++) {
    int idx = t + 256 * i;
    int col = idx >> 3, rg = idx & 7;
    float4v vv = *(const float4v*)(yt + col * 36 + rg * 4);
    *(float4v*)(out + ((size_t)b * 256 + hf * 128 + col) * 1024 + n0 +
                rg * 4) = vv;
  }
}

// ---------------------------------------------------------------------------
extern "C" void kernel_launch(void* const* d_in, const int* in_sizes, int n_in,
                              void* d_out, int out_size, void* d_ws,
                              size_t ws_size, hipStream_t stream) {
  (void)in_sizes; (void)n_in; (void)out_size; (void)ws_size;
  const float* x = (const float*)d_in[0];

  half_t* ws = (half_t*)d_ws;
  half_t* qfp = ws;                    // [16][8][1024][32] f16
  half_t* kfp = ws + 4194304;          // [16][8][1024][32] f16
  half_t* vfp = ws + 8388608;          // [16][8][32][1024] f16 (transposed)
  half_t* aop = ws + 12582912;         // [16384][256] f16
  half_t* wfp = ws + 16777216;         // 8 x 16384 f16, fragment layout
  float* tabh2 = (float*)((char*)d_ws + 33816576);  // [8][3969] f32
  float* bws = (float*)((char*)d_ws + 33943584);    // [8][128] f32

  PtrArr8 wsrc, bsrc;
  const int widx[8] = {1, 3, 5, 7, 9, 11, 13, 15};
  for (int i = 0; i < 8; i++) {
    wsrc.p[i] = (const float*)d_in[widx[i]];
    bsrc.p[i] = (const float*)d_in[widx[i] + 1];
  }

  prep_w<<<dim3(16, 8), 256, 0, stream>>>(wsrc, bsrc, wfp, bws);
  bias_mlp<<<16, 256, 0, stream>>>((const float*)d_in[18],
                                   (const float*)d_in[19],
                                   (const float*)d_in[20],
                                   (const float*)d_in[17], tabh2);
  qkv_mfma<<<dim3(512, 2), 256, 0, stream>>>(x, wfp, (const float*)d_in[17],
                                             bws, qfp, kfp, vfp);
  attn_mfma<<<1024, 256, 0, stream>>>(qfp, kfp, vfp, tabh2, aop);
  proj_mfma<<<dim3(512, 2), 256, 0, stream>>>(aop, wfp, bws, (float*)d_out);
}

// Round 3
// 190.113 us; speedup vs baseline: 1.0821x; 1.0821x over previous
//
#include <hip/hip_runtime.h>
#include <cmath>

// ---------------------------------------------------------------------------
// SwinV2-style window attention, f16-MFMA implementation.  Round 10.
//
// R9 retained (ones-column MFMA softmax denom, cvt_pkrtz P-pack, 2-deep
// software pipeline with dual P LDS buffers + double-buffered V regs).
// R9->R10: attn __launch_bounds__(256,4) -> (256).  The 4-waves/SIMD floor
// capped VGPRs at 128; the pipeline needs ~170 live -> the compiler spilled
// ~100MB/dispatch to scratch (WRITE_SIZE 8->93MB, FETCH 13.5->31MB).  No
// cap: pipeline state stays in registers, ILP covers the lower occupancy.
// ---------------------------------------------------------------------------

typedef _Float16 half_t;
typedef __attribute__((ext_vector_type(2))) __fp16 fp16x2;
typedef __attribute__((ext_vector_type(4))) _Float16 half4;
typedef __attribute__((ext_vector_type(8))) _Float16 half8;
typedef __attribute__((ext_vector_type(4))) float float4v;
typedef __attribute__((ext_vector_type(2))) unsigned int uint2v;

static __device__ __forceinline__ float4v mfma16(half8 a, half8 b, float4v c) {
  return __builtin_amdgcn_mfma_f32_16x16x32_f16(a, b, c, 0, 0, 0);
}

struct PtrArr8 { const float* p[8]; };

// ---------------------------------------------------------------------------
// prep_w: fp32 W -> f16 (+I for qkv), PRE-FRAGMENTED B-layout:
// wf[y*16384 + ((ng*4+ks)*64 + quad*16 + l)*8 + (k&7)] = W[j=ng*16+l][k](+I)
// grid (16, 8) x 256.  Biases packed to bws[y][128].
// ---------------------------------------------------------------------------
__global__ __launch_bounds__(256) void prep_w(PtrArr8 wsrc, PtrArr8 bsrc,
                                              half_t* __restrict__ wf,
                                              float* __restrict__ bws) {
  int y = blockIdx.y;
  const float* src = nullptr;
  const float* bs = nullptr;
#pragma unroll
  for (int i = 0; i < 8; i++)
    if (i == y) { src = wsrc.p[i]; bs = bsrc.p[i]; }
  int flat = (blockIdx.x * 256 + threadIdx.x) * 4;
  float4 w = *(const float4*)(src + flat);
  int j = flat >> 7, k = flat & 127;
  if (y < 6) {
    if (k == j)     w.x += 1.0f;
    if (k + 1 == j) w.y += 1.0f;
    if (k + 2 == j) w.z += 1.0f;
    if (k + 3 == j) w.w += 1.0f;
  }
  half4 h;
  h[0] = (half_t)w.x;
  h[1] = (half_t)w.y;
  h[2] = (half_t)w.z;
  h[3] = (half_t)w.w;
  int ng = j >> 4, l = j & 15, ks = k >> 5, quad = (k >> 3) & 3, o8 = k & 7;
  *(half4*)(wf + y * 16384 + ((ng * 4 + ks) * 64 + quad * 16 + l) * 8 + o8) =
      h;
  if (blockIdx.x == 0 && threadIdx.x < 128)
    bws[y * 128 + threadIdx.x] = bs[threadIdx.x];
}

// ---------------------------------------------------------------------------
// bias_mlp: tabh2[h][p] = 16*sigmoid(mlp(...))*log2e + c14(h), 63x63 grid.
// c14(h) = 14 - (scale_h + 16)*log2e; makes attn P~ = exp2(mfma result).
// ---------------------------------------------------------------------------
__global__ __launch_bounds__(256) void bias_mlp(const float* __restrict__ w1,
                                                const float* __restrict__ b1,
                                                const float* __restrict__ w2,
                                                const float* __restrict__ ls,
                                                float* __restrict__ tabh2) {
  __shared__ float sw1[256];
  __shared__ float sb1[128];
  __shared__ float sw2[1024];
  int t = threadIdx.x;
  sw1[t] = w1[t];
  if (t < 128) sb1[t] = b1[t];
  for (int i = t; i < 1024; i += 256) sw2[i] = w2[i];
  __syncthreads();
  int p = blockIdx.x * 256 + t;
  if (p >= 3969) return;
  int ph = p / 63, pw = p % 63;
  float t0 = (float)(ph - 31) * (3.2f / 31.0f);
  float t1 = (float)(pw - 31) * (3.2f / 31.0f);
  t0 = copysignf(1.0f - __expf(-fabsf(t0)), t0);
  t1 = copysignf(1.0f - __expf(-fabsf(t1)), t1);
  float acc[8];
#pragma unroll
  for (int hh = 0; hh < 8; hh++) acc[hh] = 0.0f;
  for (int j = 0; j < 128; j++) {
    float hj = fmaxf(0.0f, t0 * sw1[2 * j] + t1 * sw1[2 * j + 1] + sb1[j]);
#pragma unroll
    for (int hh = 0; hh < 8; hh++) acc[hh] += hj * sw2[hh * 128 + j];
  }
  const float L2E = 1.44269504f;
#pragma unroll
  for (int hh = 0; hh < 8; hh++) {
    float scale = __expf(fminf(ls[hh], 4.6051702f));
    float c14 = 14.0f - (scale + 16.0f) * L2E;
    float bias = 16.0f / (1.0f + __expf(-acc[hh]));
    tabh2[hh * 3969 + p] = bias * L2E + c14;
  }
}

// ---------------------------------------------------------------------------
// qkv_mfma: 3 fused linears (residual folded into W), per-head q/k norm,
// q scaled by scale*log2e.  grid (512 rowtiles-of-32, 2 hf) x 256.
// Wave (rw,cw): rows rw*16..+15, cols cw*64..+63.  W-frags direct from
// global pre-fragmented layout (1KB contiguous wave loads).  LDS only for
// the epilogue transpose.
// ---------------------------------------------------------------------------
__global__ __launch_bounds__(256, 4) void qkv_mfma(
    const float* __restrict__ x, const half_t* __restrict__ wfrag,
    const float* __restrict__ lscale, const float* __restrict__ bws,
    half_t* __restrict__ qf, half_t* __restrict__ kf,
    half_t* __restrict__ vf) {
  __shared__ half_t tbuf[4608];  // q/k: [32][136]; v: [128][36]
  int t = threadIdx.x;
  int lane = t & 63, wv = t >> 6, l = lane & 15, quad = lane >> 4;
  int rw = wv & 1, cw = wv >> 1;
  int hf = blockIdx.y;
  int m0 = blockIdx.x * 32;
  int b = m0 >> 10, n0 = m0 & 1023;

  // A fragments: 16 rows (rw strip), this half's 128 channels.
  half8 afr[4];
  {
    const float* xb =
        x + ((size_t)b * 256 + hf * 128) * 1024 + n0 + rw * 16 + l;
#pragma unroll
    for (int ks = 0; ks < 4; ks++) {
      half8 a;
#pragma unroll
      for (int j = 0; j < 8; j++)
        a[j] = (half_t)xb[(size_t)(ks * 32 + quad * 8 + j) * 1024];
      afr[ks] = a;
    }
  }

  for (int op = 0; op < 3; op++) {
    int combo = op * 2 + hf;
    const half_t* wfb = wfrag + combo * 16384;
    float4v acc[4];
#pragma unroll
    for (int ngl = 0; ngl < 4; ngl++) {
      int ng = cw * 4 + ngl;
      float4v c = {0.f, 0.f, 0.f, 0.f};
#pragma unroll
      for (int ks = 0; ks < 4; ks++) {
        half8 bfrag =
            *(const half8*)(wfb + ((ng * 4 + ks) * 64 + lane) * 8);
        c = mfma16(afr[ks], bfrag, c);
      }
      acc[ngl] = c;
    }
#pragma unroll
    for (int ngl = 0; ngl < 4; ngl++) {
      float bb = bws[combo * 128 + (cw * 4 + ngl) * 16 + l];
#pragma unroll
      for (int r2 = 0; r2 < 4; r2++) acc[ngl][r2] += bb;
    }
    if (op < 2) {
      // normalize per head: this wave's heads = hf*4 + cw*2 + {0,1}
#pragma unroll
      for (int hgl = 0; hgl < 2; hgl++) {
        float sc = 1.0f;
        if (op == 0)
          sc = __expf(fminf(lscale[hf * 4 + cw * 2 + hgl], 4.6051702f)) *
               1.44269504f;
#pragma unroll
        for (int r2 = 0; r2 < 4; r2++) {
          float ss = acc[2 * hgl][r2] * acc[2 * hgl][r2] +
                     acc[2 * hgl + 1][r2] * acc[2 * hgl + 1][r2];
          ss += __shfl_xor(ss, 1, 64);
          ss += __shfl_xor(ss, 2, 64);
          ss += __shfl_xor(ss, 4, 64);
          ss += __shfl_xor(ss, 8, 64);
          float rn = sc / fmaxf(sqrtf(ss), 1e-12f);
          acc[2 * hgl][r2] *= rn;
          acc[2 * hgl + 1][r2] *= rn;
        }
      }
      // transpose via LDS [row32][col128] stride 136 -> coalesced half8
#pragma unroll
      for (int ngl = 0; ngl < 4; ngl++)
#pragma unroll
        for (int r2 = 0; r2 < 4; r2++)
          tbuf[(rw * 16 + quad * 4 + r2) * 136 + (cw * 4 + ngl) * 16 + l] =
              (half_t)acc[ngl][r2];
      __syncthreads();
      half_t* dst = (op == 0) ? qf : kf;
#pragma unroll
      for (int i = 0; i < 2; i++) {
        int idx = t + 256 * i;
        int row = idx >> 4, colc = (idx & 15) * 8;
        half8 vv = *(const half8*)(tbuf + row * 136 + colc);
        int head = hf * 4 + (colc >> 5), d = colc & 31;
        *(half8*)(dst + (((size_t)b * 8 + head) * 1024 + n0 + row) * 32 + d) =
            vv;
      }
      __syncthreads();
    } else {
      // v: [col128][row32] stride 36 -> coalesced dword to [b][h][d][n]
#pragma unroll
      for (int ngl = 0; ngl < 4; ngl++) {
        int col = (cw * 4 + ngl) * 16 + l;
        half4 hv;
#pragma unroll
        for (int r2 = 0; r2 < 4; r2++) hv[r2] = (half_t)acc[ngl][r2];
        *(half4*)(tbuf + col * 36 + rw * 16 + quad * 4) = hv;
      }
      __syncthreads();
#pragma unroll
      for (int i = 0; i < 8; i++) {
        int idx = t + 256 * i;
        int col = idx >> 4, rp = idx & 15;
        unsigned int val = *(const unsigned int*)(tbuf + col * 36 + rp * 2);
        int head = hf * 4 + (col >> 5);
        int d = col & 31;
        *(unsigned int*)((char*)vf +
                         (((((size_t)b * 8 + head) * 32 + d) * 1024) + n0 +
                          rp * 2) * 2) = val;
      }
    }
  }
}

// ---------------------------------------------------------------------------
// attn_mfma: barrier-free flash attention, XCD-local K/V, software-pipelined.
// 1-D grid 1024: id = qo*128 + (b*8+h) -> the 8 qo-blocks of one (b,h) are
// congruent mod 8 -> same XCD -> K/V L2-resident.  256 thr (4 waves), wave
// owns 32 q-rows = one image row.  P~ = exp2(QK + biastab).
// Softmax denominator via ones-column MFMA (accl = mfma(P,1,accl): row sum
// lands directly in the O layout, row = quad*4+r2).  Dual per-wave P LDS
// buffers + double-buffered V regs give every LDS write->read and global
// load a full compute phase of slack.
// NOTE: no min-waves floor in launch_bounds — the pipeline needs ~170 live
// VGPRs; capping at 128 (R9's ",4") spilled ~100MB/dispatch to scratch.
// ---------------------------------------------------------------------------

#define LOADKV(kt, VV)                                                      \
  {                                                                         \
    _Pragma("unroll") for (int nt = 0; nt < 4; nt++)                        \
        kfr[nt] = *(const half8*)(kbase + ((kt)*64 + nt * 16 + l) * 32 +    \
                                  quad * 8);                                \
    _Pragma("unroll") for (int ks = 0; ks < 2; ks++) {                      \
      VV[0][ks] = *(const half8*)(vbase + l * 1024 + (kt)*64 + ks * 32 +    \
                                  quad * 8);                                \
      VV[1][ks] = *(const half8*)(vbase + (16 + l) * 1024 + (kt)*64 +       \
                                  ks * 32 + quad * 8);                      \
    }                                                                       \
  }

#define QK_PHASE(kt, S, SR)                                                 \
  {                                                                         \
    int rowb = (wv + 31 - 2 * (kt)) * 63 + cA + (S)*16;                     \
    _Pragma("unroll") for (int nt = 0; nt < 4; nt++) {                      \
      int base = rowb - (nt >> 1) * 63 - (nt & 1) * 16;                     \
      float4v c;                                                            \
      c[0] = sb2[base];                                                     \
      c[1] = sb2[base - 1];                                                 \
      c[2] = sb2[base - 2];                                                 \
      c[3] = sb2[base - 3];                                                 \
      SR[nt] = mfma16(kfr[nt], qfr[S], c);                                  \
    }                                                                       \
  }

#define EXP_WRITE(S, SR)                                                    \
  {                                                                         \
    half_t* paws = pa + (wv * 2 + (S)) * 1280;                              \
    _Pragma("unroll") for (int nt = 0; nt < 4; nt++) {                      \
      fp16x2 plo = __builtin_amdgcn_cvt_pkrtz(exp2f(SR[nt][0]),             \
                                              exp2f(SR[nt][1]));            \
      fp16x2 phi = __builtin_amdgcn_cvt_pkrtz(exp2f(SR[nt][2]),             \
                                              exp2f(SR[nt][3]));            \
      uint2v uu;                                                            \
      uu.x = __builtin_bit_cast(unsigned int, plo);                         \
      uu.y = __builtin_bit_cast(unsigned int, phi);                         \
      *(uint2v*)(paws + l * 80 + nt * 16 + quad * 4) = uu;                  \
    }                                                                       \
  }

#define PV_PHASE(S, VV)                                                     \
  {                                                                         \
    const half_t* paws = pa + (wv * 2 + (S)) * 1280;                        \
    _Pragma("unroll") for (int ks = 0; ks < 2; ks++) {                      \
      half8 pfr = *(const half8*)(paws + l * 80 + ks * 32 + quad * 8);      \
      o0[S] = mfma16(pfr, VV[0][ks], o0[S]);                                \
      o1[S] = mfma16(pfr, VV[1][ks], o1[S]);                                \
      accl[S] = mfma16(pfr, ones, accl[S]);                                 \
    }                                                                       \
  }

// phase order per kt: QK(s0) -> PV(prev kt,s1) -> exp/wr(s0) -> QK(s1) ->
// prefetch(kt+1) -> PV(kt,s0) -> exp/wr(s1)
#define ITER(kt, VC, VN, DO_PREV, DO_PREF)                                  \
  {                                                                         \
    float4v sres[4];                                                        \
    QK_PHASE(kt, 0, sres);                                                  \
    if (DO_PREV) PV_PHASE(1, VN);                                           \
    EXP_WRITE(0, sres);                                                     \
    float4v sres2[4];                                                       \
    QK_PHASE(kt, 1, sres2);                                                 \
    if (DO_PREF) LOADKV((kt) + 1, VN);                                      \
    PV_PHASE(0, VC);                                                        \
    EXP_WRITE(1, sres2);                                                    \
  }

__global__ __launch_bounds__(256) void attn_mfma(
    const half_t* __restrict__ qf, const half_t* __restrict__ kf,
    const half_t* __restrict__ vf, const float* __restrict__ tabh2,
    half_t* __restrict__ ao) {
  __shared__ float sb2[35 * 63];    // bias slice: dih-local in [0,35)
  __shared__ half_t pa[10240];      // per-wave dual P~ buffers [16][80]

  int id = blockIdx.x;
  int qo = id >> 7;
  int bh = id & 127;
  int h = bh & 7, b = bh >> 3;
  int t = threadIdx.x;
  int lane = t & 63, wv = t >> 6, l = lane & 15, quad = lane >> 4;
  size_t bhs = (size_t)b * 8 + h;
  const half_t* kbase = kf + bhs * 1024 * 32;
  const half_t* vbase = vf + bhs * 32 * 1024;
  int row0 = qo * 128 + wv * 32;
  int cA = l + 31 - quad * 4;

  half8 kfr[4], va[2][2], vb[2][2], qfr[2];
  LOADKV(0, va);
#pragma unroll
  for (int s = 0; s < 2; s++)
    qfr[s] = *(const half8*)(qf + (bhs * 1024 + row0 + s * 16 + l) * 32 +
                             quad * 8);

  // stage bias slice: dih_global in [qo*4, qo*4+35)
  for (int i = t; i < 2205; i += 256)
    sb2[i] = tabh2[h * 3969 + qo * 252 + i];

  float4v o0[2], o1[2], accl[2];
#pragma unroll
  for (int s = 0; s < 2; s++) {
    o0[s] = (float4v){0.f, 0.f, 0.f, 0.f};
    o1[s] = (float4v){0.f, 0.f, 0.f, 0.f};
    accl[s] = (float4v){0.f, 0.f, 0.f, 0.f};
  }
  half8 ones;
#pragma unroll
  for (int j = 0; j < 8; j++) ones[j] = (half_t)1.0f;

  __syncthreads();  // the ONLY barrier

  ITER(0, va, vb, 0, 1);
  ITER(1, vb, va, 1, 1);
  for (int kt2 = 2; kt2 < 14; kt2 += 2) {
    ITER(kt2, va, vb, 1, 1);
    ITER(kt2 + 1, vb, va, 1, 1);
  }
  ITER(14, va, vb, 1, 1);
  ITER(15, vb, va, 1, 0);
  PV_PHASE(1, vb);  // drain (kt=15, s=1)

#pragma unroll
  for (int s = 0; s < 2; s++) {
#pragma unroll
    for (int r2 = 0; r2 < 4; r2++) {
      float linv = 1.0f / accl[s][r2];
      size_t rowaddr =
          ((size_t)b * 1024 + row0 + s * 16 + quad * 4 + r2) * 256 + h * 32;
      ao[rowaddr + l] = (half_t)(o0[s][r2] * linv);
      ao[rowaddr + 16 + l] = (half_t)(o1[s][r2] * linv);
    }
  }
}

// ---------------------------------------------------------------------------
// proj_mfma: output projection, fp32 out [b][ch][n] via LDS transpose.
// grid (512 rowtiles-of-32, 2 hf) x 256.  W-frags direct from global.
// ---------------------------------------------------------------------------
__global__ __launch_bounds__(256, 4) void proj_mfma(
    const half_t* __restrict__ ao, const half_t* __restrict__ wfrag,
    const float* __restrict__ bws, float* __restrict__ out) {
  __shared__ float yt[128 * 36];
  int t = threadIdx.x;
  int lane = t & 63, wv = t >> 6, l = lane & 15, quad = lane >> 4;
  int rw = wv & 1, cw = wv >> 1;
  int hf = blockIdx.y;
  int m0 = blockIdx.x * 32;
  int b = m0 >> 10, n0 = m0 & 1023;

  half8 afr[4];
  const half_t* ab =
      ao + ((size_t)m0 + rw * 16 + l) * 256 + hf * 128 + quad * 8;
#pragma unroll
  for (int ks = 0; ks < 4; ks++) afr[ks] = *(const half8*)(ab + ks * 32);

  const half_t* wfb = wfrag + (6 + hf) * 16384;
#pragma unroll
  for (int ngl = 0; ngl < 4; ngl++) {
    int ng = cw * 4 + ngl;
    float4v c = {0.f, 0.f, 0.f, 0.f};
#pragma unroll
    for (int ks = 0; ks < 4; ks++) {
      half8 bfrag = *(const half8*)(wfb + ((ng * 4 + ks) * 64 + lane) * 8);
      c = mfma16(afr[ks], bfrag, c);
    }
    float bb = bws[(6 + hf) * 128 + ng * 16 + l];
#pragma unroll
    for (int r2 = 0; r2 < 4; r2++) c[r2] += bb;
    *(float4v*)(yt + (ng * 16 + l) * 36 + rw * 16 + quad * 4) = c;
  }
  __syncthreads();
#pragma unroll
  for (int i = 0; i < 4; i++) {
    int idx = t + 256 * i;
    int col = idx >> 3, rg = idx & 7;
    float4v vv = *(const float4v*)(yt + col * 36 + rg * 4);
    *(float4v*)(out + ((size_t)b * 256 + hf * 128 + col) * 1024 + n0 +
                rg * 4) = vv;
  }
}

// ---------------------------------------------------------------------------
extern "C" void kernel_launch(void* const* d_in, const int* in_sizes, int n_in,
                              void* d_out, int out_size, void* d_ws,
                              size_t ws_size, hipStream_t stream) {
  (void)in_sizes; (void)n_in; (void)out_size; (void)ws_size;
  const float* x = (const float*)d_in[0];

  half_t* ws = (half_t*)d_ws;
  half_t* qfp = ws;                    // [16][8][1024][32] f16
  half_t* kfp = ws + 4194304;          // [16][8][1024][32] f16
  half_t* vfp = ws + 8388608;          // [16][8][32][1024] f16 (transposed)
  half_t* aop = ws + 12582912;         // [16384][256] f16
  half_t* wfp = ws + 16777216;         // 8 x 16384 f16, fragment layout
  float* tabh2 = (float*)((char*)d_ws + 33816576);  // [8][3969] f32
  float* bws = (float*)((char*)d_ws + 33943584);    // [8][128] f32

  PtrArr8 wsrc, bsrc;
  const int widx[8] = {1, 3, 5, 7, 9, 11, 13, 15};
  for (int i = 0; i < 8; i++) {
    wsrc.p[i] = (const float*)d_in[widx[i]];
    bsrc.p[i] = (const float*)d_in[widx[i] + 1];
  }

  prep_w<<<dim3(16, 8), 256, 0, stream>>>(wsrc, bsrc, wfp, bws);
  bias_mlp<<<16, 256, 0, stream>>>((const float*)d_in[18],
                                   (const float*)d_in[19],
                                   (const float*)d_in[20],
                                   (const float*)d_in[17], tabh2);
  qkv_mfma<<<dim3(512, 2), 256, 0, stream>>>(x, wfp, (const float*)d_in[17],
                                             bws, qfp, kfp, vfp);
  attn_mfma<<<1024, 256, 0, stream>>>(qfp, kfp, vfp, tabh2, aop);
  proj_mfma<<<dim3(512, 2), 256, 0, stream>>>(aop, wfp, bws, (float*)d_out);
}

// Round 4
// 189.619 us; speedup vs baseline: 1.0849x; 1.0026x over previous
//
#include <hip/hip_runtime.h>
#include <cmath>

// ---------------------------------------------------------------------------
// SwinV2-style window attention, f16-MFMA implementation.  Round 11.
//
// R10->R11 (attn_mfma only) — LDS-pipe relief (model: ~40us of 63.5us was
// LDS ops + bank conflicts):
//  * P~ buffer: row stride 80 -> 72 halves (36 words, 36 mod 32 = 4) with
//    XOR swizzle p=((l>>3)&1)<<2 on the 8-half granule index.  Enumerated:
//    P writes (b64) and P reads (b128) both conflict-free (was 4-way:
//    stride-40-words made rows l, l+4, l+8, l+12 alias -> measured 96
//    conflict-cycles per wave per kt = the whole 6.29M counter).
//  * bias table staged as pair-replicated float2 sb2d[i]={tab[i-1],tab[i]}:
//    the 4 MFMA C-inputs are consecutive descending floats -> 32
//    ds_read_b32 per kt/wave become 16 aligned ds_read_b64.  f32 exact.
// ---------------------------------------------------------------------------

typedef _Float16 half_t;
typedef __attribute__((ext_vector_type(2))) __fp16 fp16x2;
typedef __attribute__((ext_vector_type(4))) _Float16 half4;
typedef __attribute__((ext_vector_type(8))) _Float16 half8;
typedef __attribute__((ext_vector_type(2))) float float2v;
typedef __attribute__((ext_vector_type(4))) float float4v;
typedef __attribute__((ext_vector_type(2))) unsigned int uint2v;

static __device__ __forceinline__ float4v mfma16(half8 a, half8 b, float4v c) {
  return __builtin_amdgcn_mfma_f32_16x16x32_f16(a, b, c, 0, 0, 0);
}

struct PtrArr8 { const float* p[8]; };

// ---------------------------------------------------------------------------
// prep_w: fp32 W -> f16 (+I for qkv), PRE-FRAGMENTED B-layout:
// wf[y*16384 + ((ng*4+ks)*64 + quad*16 + l)*8 + (k&7)] = W[j=ng*16+l][k](+I)
// grid (16, 8) x 256.  Biases packed to bws[y][128].
// ---------------------------------------------------------------------------
__global__ __launch_bounds__(256) void prep_w(PtrArr8 wsrc, PtrArr8 bsrc,
                                              half_t* __restrict__ wf,
                                              float* __restrict__ bws) {
  int y = blockIdx.y;
  const float* src = nullptr;
  const float* bs = nullptr;
#pragma unroll
  for (int i = 0; i < 8; i++)
    if (i == y) { src = wsrc.p[i]; bs = bsrc.p[i]; }
  int flat = (blockIdx.x * 256 + threadIdx.x) * 4;
  float4 w = *(const float4*)(src + flat);
  int j = flat >> 7, k = flat & 127;
  if (y < 6) {
    if (k == j)     w.x += 1.0f;
    if (k + 1 == j) w.y += 1.0f;
    if (k + 2 == j) w.z += 1.0f;
    if (k + 3 == j) w.w += 1.0f;
  }
  half4 h;
  h[0] = (half_t)w.x;
  h[1] = (half_t)w.y;
  h[2] = (half_t)w.z;
  h[3] = (half_t)w.w;
  int ng = j >> 4, l = j & 15, ks = k >> 5, quad = (k >> 3) & 3, o8 = k & 7;
  *(half4*)(wf + y * 16384 + ((ng * 4 + ks) * 64 + quad * 16 + l) * 8 + o8) =
      h;
  if (blockIdx.x == 0 && threadIdx.x < 128)
    bws[y * 128 + threadIdx.x] = bs[threadIdx.x];
}

// ---------------------------------------------------------------------------
// bias_mlp: tabh2[h][p] = 16*sigmoid(mlp(...))*log2e + c14(h), 63x63 grid.
// c14(h) = 14 - (scale_h + 16)*log2e; makes attn P~ = exp2(mfma result).
// ---------------------------------------------------------------------------
__global__ __launch_bounds__(256) void bias_mlp(const float* __restrict__ w1,
                                                const float* __restrict__ b1,
                                                const float* __restrict__ w2,
                                                const float* __restrict__ ls,
                                                float* __restrict__ tabh2) {
  __shared__ float sw1[256];
  __shared__ float sb1[128];
  __shared__ float sw2[1024];
  int t = threadIdx.x;
  sw1[t] = w1[t];
  if (t < 128) sb1[t] = b1[t];
  for (int i = t; i < 1024; i += 256) sw2[i] = w2[i];
  __syncthreads();
  int p = blockIdx.x * 256 + t;
  if (p >= 3969) return;
  int ph = p / 63, pw = p % 63;
  float t0 = (float)(ph - 31) * (3.2f / 31.0f);
  float t1 = (float)(pw - 31) * (3.2f / 31.0f);
  t0 = copysignf(1.0f - __expf(-fabsf(t0)), t0);
  t1 = copysignf(1.0f - __expf(-fabsf(t1)), t1);
  float acc[8];
#pragma unroll
  for (int hh = 0; hh < 8; hh++) acc[hh] = 0.0f;
  for (int j = 0; j < 128; j++) {
    float hj = fmaxf(0.0f, t0 * sw1[2 * j] + t1 * sw1[2 * j + 1] + sb1[j]);
#pragma unroll
    for (int hh = 0; hh < 8; hh++) acc[hh] += hj * sw2[hh * 128 + j];
  }
  const float L2E = 1.44269504f;
#pragma unroll
  for (int hh = 0; hh < 8; hh++) {
    float scale = __expf(fminf(ls[hh], 4.6051702f));
    float c14 = 14.0f - (scale + 16.0f) * L2E;
    float bias = 16.0f / (1.0f + __expf(-acc[hh]));
    tabh2[hh * 3969 + p] = bias * L2E + c14;
  }
}

// ---------------------------------------------------------------------------
// qkv_mfma: 3 fused linears (residual folded into W), per-head q/k norm,
// q scaled by scale*log2e.  grid (512 rowtiles-of-32, 2 hf) x 256.
// Wave (rw,cw): rows rw*16..+15, cols cw*64..+63.  W-frags direct from
// global pre-fragmented layout (1KB contiguous wave loads).  LDS only for
// the epilogue transpose.
// ---------------------------------------------------------------------------
__global__ __launch_bounds__(256, 4) void qkv_mfma(
    const float* __restrict__ x, const half_t* __restrict__ wfrag,
    const float* __restrict__ lscale, const float* __restrict__ bws,
    half_t* __restrict__ qf, half_t* __restrict__ kf,
    half_t* __restrict__ vf) {
  __shared__ half_t tbuf[4608];  // q/k: [32][136]; v: [128][36]
  int t = threadIdx.x;
  int lane = t & 63, wv = t >> 6, l = lane & 15, quad = lane >> 4;
  int rw = wv & 1, cw = wv >> 1;
  int hf = blockIdx.y;
  int m0 = blockIdx.x * 32;
  int b = m0 >> 10, n0 = m0 & 1023;

  // A fragments: 16 rows (rw strip), this half's 128 channels.
  half8 afr[4];
  {
    const float* xb =
        x + ((size_t)b * 256 + hf * 128) * 1024 + n0 + rw * 16 + l;
#pragma unroll
    for (int ks = 0; ks < 4; ks++) {
      half8 a;
#pragma unroll
      for (int j = 0; j < 8; j++)
        a[j] = (half_t)xb[(size_t)(ks * 32 + quad * 8 + j) * 1024];
      afr[ks] = a;
    }
  }

  for (int op = 0; op < 3; op++) {
    int combo = op * 2 + hf;
    const half_t* wfb = wfrag + combo * 16384;
    float4v acc[4];
#pragma unroll
    for (int ngl = 0; ngl < 4; ngl++) {
      int ng = cw * 4 + ngl;
      float4v c = {0.f, 0.f, 0.f, 0.f};
#pragma unroll
      for (int ks = 0; ks < 4; ks++) {
        half8 bfrag =
            *(const half8*)(wfb + ((ng * 4 + ks) * 64 + lane) * 8);
        c = mfma16(afr[ks], bfrag, c);
      }
      acc[ngl] = c;
    }
#pragma unroll
    for (int ngl = 0; ngl < 4; ngl++) {
      float bb = bws[combo * 128 + (cw * 4 + ngl) * 16 + l];
#pragma unroll
      for (int r2 = 0; r2 < 4; r2++) acc[ngl][r2] += bb;
    }
    if (op < 2) {
      // normalize per head: this wave's heads = hf*4 + cw*2 + {0,1}
#pragma unroll
      for (int hgl = 0; hgl < 2; hgl++) {
        float sc = 1.0f;
        if (op == 0)
          sc = __expf(fminf(lscale[hf * 4 + cw * 2 + hgl], 4.6051702f)) *
               1.44269504f;
#pragma unroll
        for (int r2 = 0; r2 < 4; r2++) {
          float ss = acc[2 * hgl][r2] * acc[2 * hgl][r2] +
                     acc[2 * hgl + 1][r2] * acc[2 * hgl + 1][r2];
          ss += __shfl_xor(ss, 1, 64);
          ss += __shfl_xor(ss, 2, 64);
          ss += __shfl_xor(ss, 4, 64);
          ss += __shfl_xor(ss, 8, 64);
          float rn = sc / fmaxf(sqrtf(ss), 1e-12f);
          acc[2 * hgl][r2] *= rn;
          acc[2 * hgl + 1][r2] *= rn;
        }
      }
      // transpose via LDS [row32][col128] stride 136 -> coalesced half8
#pragma unroll
      for (int ngl = 0; ngl < 4; ngl++)
#pragma unroll
        for (int r2 = 0; r2 < 4; r2++)
          tbuf[(rw * 16 + quad * 4 + r2) * 136 + (cw * 4 + ngl) * 16 + l] =
              (half_t)acc[ngl][r2];
      __syncthreads();
      half_t* dst = (op == 0) ? qf : kf;
#pragma unroll
      for (int i = 0; i < 2; i++) {
        int idx = t + 256 * i;
        int row = idx >> 4, colc = (idx & 15) * 8;
        half8 vv = *(const half8*)(tbuf + row * 136 + colc);
        int head = hf * 4 + (colc >> 5), d = colc & 31;
        *(half8*)(dst + (((size_t)b * 8 + head) * 1024 + n0 + row) * 32 + d) =
            vv;
      }
      __syncthreads();
    } else {
      // v: [col128][row32] stride 36 -> coalesced dword to [b][h][d][n]
#pragma unroll
      for (int ngl = 0; ngl < 4; ngl++) {
        int col = (cw * 4 + ngl) * 16 + l;
        half4 hv;
#pragma unroll
        for (int r2 = 0; r2 < 4; r2++) hv[r2] = (half_t)acc[ngl][r2];
        *(half4*)(tbuf + col * 36 + rw * 16 + quad * 4) = hv;
      }
      __syncthreads();
#pragma unroll
      for (int i = 0; i < 8; i++) {
        int idx = t + 256 * i;
        int col = idx >> 4, rp = idx & 15;
        unsigned int val = *(const unsigned int*)(tbuf + col * 36 + rp * 2);
        int head = hf * 4 + (col >> 5);
        int d = col & 31;
        *(unsigned int*)((char*)vf +
                         (((((size_t)b * 8 + head) * 32 + d) * 1024) + n0 +
                          rp * 2) * 2) = val;
      }
    }
  }
}

// ---------------------------------------------------------------------------
// attn_mfma: barrier-free flash attention, XCD-local K/V, software-pipelined.
// 1-D grid 1024: id = qo*128 + (b*8+h) -> the 8 qo-blocks of one (b,h) are
// congruent mod 8 -> same XCD -> K/V L2-resident.  256 thr (4 waves), wave
// owns 32 q-rows = one image row.  P~ = exp2(QK + biastab).
// Softmax denom via ones-column MFMA.  P~ buffer: stride 72 halves + XOR
// swizzle (conflict-free).  Bias C-inputs: pair-replicated float2 -> b64.
// ---------------------------------------------------------------------------

#define LOADKV(kt, VV)                                                      \
  {                                                                         \
    _Pragma("unroll") for (int nt = 0; nt < 4; nt++)                        \
        kfr[nt] = *(const half8*)(kbase + ((kt)*64 + nt * 16 + l) * 32 +    \
                                  quad * 8);                                \
    _Pragma("unroll") for (int ks = 0; ks < 2; ks++) {                      \
      VV[0][ks] = *(const half8*)(vbase + l * 1024 + (kt)*64 + ks * 32 +    \
                                  quad * 8);                                \
      VV[1][ks] = *(const half8*)(vbase + (16 + l) * 1024 + (kt)*64 +       \
                                  ks * 32 + quad * 8);                      \
    }                                                                       \
  }

#define QK_PHASE(kt, S, SR)                                                 \
  {                                                                         \
    int rowb = (wv + 31 - 2 * (kt)) * 63 + cA + (S)*16;                     \
    _Pragma("unroll") for (int nt = 0; nt < 4; nt++) {                      \
      int base = rowb - (nt >> 1) * 63 - (nt & 1) * 16;                     \
      float2v p0 = sb2d[base];                                              \
      float2v p1 = sb2d[base - 2];                                          \
      float4v c;                                                            \
      c[0] = p0[1];                                                         \
      c[1] = p0[0];                                                         \
      c[2] = p1[1];                                                         \
      c[3] = p1[0];                                                         \
      SR[nt] = mfma16(kfr[nt], qfr[S], c);                                  \
    }                                                                       \
  }

#define EXP_WRITE(S, SR)                                                    \
  {                                                                         \
    half_t* paws = pa + (wv * 2 + (S)) * 1152;                              \
    _Pragma("unroll") for (int nt = 0; nt < 4; nt++) {                      \
      fp16x2 plo = __builtin_amdgcn_cvt_pkrtz(exp2f(SR[nt][0]),             \
                                              exp2f(SR[nt][1]));            \
      fp16x2 phi = __builtin_amdgcn_cvt_pkrtz(exp2f(SR[nt][2]),             \
                                              exp2f(SR[nt][3]));            \
      uint2v uu;                                                            \
      uu.x = __builtin_bit_cast(unsigned int, plo);                         \
      uu.y = __builtin_bit_cast(unsigned int, phi);                         \
      *(uint2v*)(paws + l * 72 +                                            \
                 (((nt * 2 + (quad >> 1)) ^ pswz) << 3) +                   \
                 ((quad & 1) << 2)) = uu;                                   \
    }                                                                       \
  }

#define PV_PHASE(S, VV)                                                     \
  {                                                                         \
    const half_t* paws = pa + (wv * 2 + (S)) * 1152;                        \
    _Pragma("unroll") for (int ks = 0; ks < 2; ks++) {                      \
      half8 pfr = *(const half8*)(paws + l * 72 +                           \
                                  (((ks * 4 + quad) ^ pswz) << 3));         \
      o0[S] = mfma16(pfr, VV[0][ks], o0[S]);                                \
      o1[S] = mfma16(pfr, VV[1][ks], o1[S]);                                \
      accl[S] = mfma16(pfr, ones, accl[S]);                                 \
    }                                                                       \
  }

// phase order per kt: QK(s0) -> PV(prev kt,s1) -> exp/wr(s0) -> QK(s1) ->
// prefetch(kt+1) -> PV(kt,s0) -> exp/wr(s1)
#define ITER(kt, VC, VN, DO_PREV, DO_PREF)                                  \
  {                                                                         \
    float4v sres[4];                                                        \
    QK_PHASE(kt, 0, sres);                                                  \
    if (DO_PREV) PV_PHASE(1, VN);                                           \
    EXP_WRITE(0, sres);                                                     \
    float4v sres2[4];                                                       \
    QK_PHASE(kt, 1, sres2);                                                 \
    if (DO_PREF) LOADKV((kt) + 1, VN);                                      \
    PV_PHASE(0, VC);                                                        \
    EXP_WRITE(1, sres2);                                                    \
  }

__global__ __launch_bounds__(256) void attn_mfma(
    const half_t* __restrict__ qf, const half_t* __restrict__ kf,
    const half_t* __restrict__ vf, const float* __restrict__ tabh2,
    half_t* __restrict__ ao) {
  __shared__ float2v sb2d[2205];   // bias pairs {tab[i-1], tab[i]}, 17.6KB
  __shared__ half_t pa[9216];      // per-wave dual P~ buffers [16][72] swz

  int id = blockIdx.x;
  int qo = id >> 7;
  int bh = id & 127;
  int h = bh & 7, b = bh >> 3;
  int t = threadIdx.x;
  int lane = t & 63, wv = t >> 6, l = lane & 15, quad = lane >> 4;
  size_t bhs = (size_t)b * 8 + h;
  const half_t* kbase = kf + bhs * 1024 * 32;
  const half_t* vbase = vf + bhs * 32 * 1024;
  int row0 = qo * 128 + wv * 32;
  int cA = l + 31 - quad * 4;
  int pswz = (l >> 3) << 2;  // XOR swizzle on 8-half granule index

  half8 kfr[4], va[2][2], vb[2][2], qfr[2];
  LOADKV(0, va);
#pragma unroll
  for (int s = 0; s < 2; s++)
    qfr[s] = *(const half8*)(qf + (bhs * 1024 + row0 + s * 16 + l) * 32 +
                             quad * 8);

  // stage bias slice as descending pairs: dih_global in [qo*4, qo*4+35)
  {
    const float* tb = tabh2 + h * 3969 + qo * 252;
    for (int i = t; i < 2205; i += 256) {
      float2v pr;
      pr[0] = (i > 0) ? tb[i - 1] : 0.0f;
      pr[1] = tb[i];
      sb2d[i] = pr;
    }
  }

  float4v o0[2], o1[2], accl[2];
#pragma unroll
  for (int s = 0; s < 2; s++) {
    o0[s] = (float4v){0.f, 0.f, 0.f, 0.f};
    o1[s] = (float4v){0.f, 0.f, 0.f, 0.f};
    accl[s] = (float4v){0.f, 0.f, 0.f, 0.f};
  }
  half8 ones;
#pragma unroll
  for (int j = 0; j < 8; j++) ones[j] = (half_t)1.0f;

  __syncthreads();  // the ONLY barrier

  ITER(0, va, vb, 0, 1);
  ITER(1, vb, va, 1, 1);
  for (int kt2 = 2; kt2 < 14; kt2 += 2) {
    ITER(kt2, va, vb, 1, 1);
    ITER(kt2 + 1, vb, va, 1, 1);
  }
  ITER(14, va, vb, 1, 1);
  ITER(15, vb, va, 1, 0);
  PV_PHASE(1, vb);  // drain (kt=15, s=1)

#pragma unroll
  for (int s = 0; s < 2; s++) {
#pragma unroll
    for (int r2 = 0; r2 < 4; r2++) {
      float linv = 1.0f / accl[s][r2];
      size_t rowaddr =
          ((size_t)b * 1024 + row0 + s * 16 + quad * 4 + r2) * 256 + h * 32;
      ao[rowaddr + l] = (half_t)(o0[s][r2] * linv);
      ao[rowaddr + 16 + l] = (half_t)(o1[s][r2] * linv);
    }
  }
}

// ---------------------------------------------------------------------------
// proj_mfma: output projection, fp32 out [b][ch][n] via LDS transpose.
// grid (512 rowtiles-of-32, 2 hf) x 256.  W-frags direct from global.
// ---------------------------------------------------------------------------
__global__ __launch_bounds__(256, 4) void proj_mfma(
    const half_t* __restrict__ ao, const half_t* __restrict__ wfrag,
    const float* __restrict__ bws, float* __restrict__ out) {
  __shared__ float yt[128 * 36];
  int t = threadIdx.x;
  int lane = t & 63, wv = t >> 6, l = lane & 15, quad = lane >> 4;
  int rw = wv & 1, cw = wv >> 1;
  int hf = blockIdx.y;
  int m0 = blockIdx.x * 32;
  int b = m0 >> 10, n0 = m0 & 1023;

  half8 afr[4];
  const half_t* ab =
      ao + ((size_t)m0 + rw * 16 + l) * 256 + hf * 128 + quad * 8;
#pragma unroll
  for (int ks = 0; ks < 4; ks++) afr[ks] = *(const half8*)(ab + ks * 32);

  const half_t* wfb = wfrag + (6 + hf) * 16384;
#pragma unroll
  for (int ngl = 0; ngl < 4; ngl++) {
    int ng = cw * 4 + ngl;
    float4v c = {0.f, 0.f, 0.f, 0.f};
#pragma unroll
    for (int ks = 0; ks < 4; ks++) {
      half8 bfrag = *(const half8*)(wfb + ((ng * 4 + ks) * 64 + lane) * 8);
      c = mfma16(afr[ks], bfrag, c);
    }
    float bb = bws[(6 + hf) * 128 + ng * 16 + l];
#pragma unroll
    for (int r2 = 0; r2 < 4; r2++) c[r2] += bb;
    *(float4v*)(yt + (ng * 16 + l) * 36 + rw * 16 + quad * 4) = c;
  }
  __syncthreads();
#pragma unroll
  for (int i = 0; i < 4; i++) {
    int idx = t + 256 * i;
    int col = idx >> 3, rg = idx & 7;
    float4v vv = *(const float4v*)(yt + col * 36 + rg * 4);
    *(float4v*)(out + ((size_t)b * 256 + hf * 128 + col) * 1024 + n0 +
                rg * 4) = vv;
  }
}

// ---------------------------------------------------------------------------
extern "C" void kernel_launch(void* const* d_in, const int* in_sizes, int n_in,
                              void* d_out, int out_size, void* d_ws,
                              size_t ws_size, hipStream_t stream) {
  (void)in_sizes; (void)n_in; (void)out_size; (void)ws_size;
  const float* x = (const float*)d_in[0];

  half_t* ws = (half_t*)d_ws;
  half_t* qfp = ws;                    // [16][8][1024][32] f16
  half_t* kfp = ws + 4194304;          // [16][8][1024][32] f16
  half_t* vfp = ws + 8388608;          // [16][8][32][1024] f16 (transposed)
  half_t* aop = ws + 12582912;         // [16384][256] f16
  half_t* wfp = ws + 16777216;         // 8 x 16384 f16, fragment layout
  float* tabh2 = (float*)((char*)d_ws + 33816576);  // [8][3969] f32
  float* bws = (float*)((char*)d_ws + 33943584);    // [8][128] f32

  PtrArr8 wsrc, bsrc;
  const int widx[8] = {1, 3, 5, 7, 9, 11, 13, 15};
  for (int i = 0; i < 8; i++) {
    wsrc.p[i] = (const float*)d_in[widx[i]];
    bsrc.p[i] = (const float*)d_in[widx[i] + 1];
  }

  prep_w<<<dim3(16, 8), 256, 0, stream>>>(wsrc, bsrc, wfp, bws);
  bias_mlp<<<16, 256, 0, stream>>>((const float*)d_in[18],
                                   (const float*)d_in[19],
                                   (const float*)d_in[20],
                                   (const float*)d_in[17], tabh2);
  qkv_mfma<<<dim3(512, 2), 256, 0, stream>>>(x, wfp, (const float*)d_in[17],
                                             bws, qfp, kfp, vfp);
  attn_mfma<<<1024, 256, 0, stream>>>(qfp, kfp, vfp, tabh2, aop);
  proj_mfma<<<dim3(512, 2), 256, 0, stream>>>(aop, wfp, bws, (float*)d_out);
}